// Round 6
// baseline (258.872 us; speedup 1.0000x reference)
//
#include <hip/hip_runtime.h>
#include <hip/hip_bf16.h>
#include <hip/hip_fp16.h>
#include <math.h>

// GCN link prediction. R17 = R16 (257.6us) with GEMM1 fused into pS2's
// epilogue (pS2G): the bucket sort block already holds the bucket's degrees
// in LDS, so it computes ts1h for its own 512 nodes (2 threads/node K-split,
// W1 staged in LDS) right after the scatter. Deletes the standalone gemm1
// launch slot (~35us, ran at 1.5 waves/SIMD); fused gemm runs at pS2's 3
// waves/SIMD and overlaps the scatter-write latency.
//   deg[v] = incount(col==v)+1 ; dinv = rsqrt(deg)
//   ts[v]  = (h[v]@W)*dinv[v]          (fp16 gather tables, L2-resident)
//   h'[c]  = act(dinv[c]*(sum_{e:col=c} ts[row_e] + ts[c]) + b)
//   score  = sigmoid(dot(h2[row], h2[col]))

#define BSH 9
#define BSZ 512            // nodes per bucket -> NBUK = 196 (<= 256)
#define CAPB 32768         // slots per bucket (2x avg 16327; +128 sigma)
#define MAXCH 3200         // edges per chunk (multiple of 4)
#define MAXCHUNKS 1024

// ---- pSort: chunk histogram -> atomic base grab -> LDS bucket-order ->
//      coalesced run writes into fixed-capacity bucket regions ----
__global__ __launch_bounds__(512) void pSort(
    const int* __restrict__ row, const int* __restrict__ col,
    int* __restrict__ gcur, unsigned int* __restrict__ ebuf,
    int E, int CH, int NBUK) {
    __shared__ unsigned int se[MAXCH];        // chunk edges, bucket-ordered
    __shared__ unsigned short pk[MAXCH];      // bucket id per LDS slot
    __shared__ int lhist[256], lbase[256], lcur[256], gbase[256];
    const int t = threadIdx.x, b = blockIdx.x;
    if (t < 256) lhist[t] = 0;
    __syncthreads();
    const int s = b * CH, e = min(E, s + CH);
    const int cnt = e - s;
    const int n4 = cnt >> 2;
    const int4* c4 = (const int4*)(col + s);
    const int4* r4 = (const int4*)(row + s);
    for (int i = t; i < n4; i += 512) {
        int4 c = c4[i];
        atomicAdd(&lhist[c.x >> BSH], 1);
        atomicAdd(&lhist[c.y >> BSH], 1);
        atomicAdd(&lhist[c.z >> BSH], 1);
        atomicAdd(&lhist[c.w >> BSH], 1);
    }
    for (int i = (n4 << 2) + t; i < cnt; i += 512) atomicAdd(&lhist[col[s + i] >> BSH], 1);
    __syncthreads();
    {   // 256-wide exclusive scan of lhist -> lbase (scratch in lcur); threads 0-255
        int own = (t < 256) ? lhist[t] : 0;
        if (t < 256) lcur[t] = own;
        __syncthreads();
        for (int d = 1; d < 256; d <<= 1) {
            int add = (t < 256 && t >= d) ? lcur[t - d] : 0;
            __syncthreads();
            if (t < 256) lcur[t] += add;
            __syncthreads();
        }
        if (t < 256) {
            lbase[t] = lcur[t] - own;
            lcur[t] = lcur[t] - own;
        }
        __syncthreads();
        if (t < NBUK) {   // grab this chunk's range in bucket t
            int base = atomicAdd(&gcur[t], lhist[t]);
            gbase[t] = t * CAPB + base - lbase[t];
        }
    }
    __syncthreads();
    // placement into LDS (bucket-ordered)
    for (int i = t; i < n4; i += 512) {
        int4 c = c4[i];
        int4 r = r4[i];
        int k0 = c.x >> BSH, p0 = atomicAdd(&lcur[k0], 1);
        se[p0] = ((unsigned int)(c.x & (BSZ - 1)) << 17) | (unsigned int)r.x; pk[p0] = (unsigned short)k0;
        int k1 = c.y >> BSH, p1 = atomicAdd(&lcur[k1], 1);
        se[p1] = ((unsigned int)(c.y & (BSZ - 1)) << 17) | (unsigned int)r.y; pk[p1] = (unsigned short)k1;
        int k2 = c.z >> BSH, p2 = atomicAdd(&lcur[k2], 1);
        se[p2] = ((unsigned int)(c.z & (BSZ - 1)) << 17) | (unsigned int)r.z; pk[p2] = (unsigned short)k2;
        int k3 = c.w >> BSH, p3 = atomicAdd(&lcur[k3], 1);
        se[p3] = ((unsigned int)(c.w & (BSZ - 1)) << 17) | (unsigned int)r.w; pk[p3] = (unsigned short)k3;
    }
    for (int i = (n4 << 2) + t; i < cnt; i += 512) {
        int c = col[s + i], r = row[s + i];
        int k = c >> BSH, p = atomicAdd(&lcur[k], 1);
        se[p] = ((unsigned int)(c & (BSZ - 1)) << 17) | (unsigned int)r; pk[p] = (unsigned short)k;
    }
    __syncthreads();
    // coalesced write-out: consecutive LDS slots in a bucket -> consecutive global
    for (int i = t; i < cnt; i += 512) {
        int k = pk[i];
        ebuf[gbase[k] + i] = se[i];
    }
}

// ---- pS2G: in-bucket counting sort by local col (emits dinv + CSR start)
//      + fused GEMM1 for the bucket's nodes (2 threads/node K-split) ----
__global__ __launch_bounds__(1024) void pS2G(
    const unsigned int* __restrict__ ebuf, const int* __restrict__ gcur,
    const float* __restrict__ x, const float* __restrict__ W1,
    unsigned int* __restrict__ ebuf2, float* __restrict__ dinv,
    int* __restrict__ start, __half* __restrict__ ts, int N) {
    __shared__ int h[BSZ], sc[BSZ], cur[BSZ];
    __shared__ float wsT[16 * 132];
    const int t = threadIdx.x, k = blockIdx.x;
    if (t < BSZ) h[t] = 0;
    // stage W1 transposed: wsT[c*132+k] = W1[k*16+c]
    for (int idx = t; idx < 2048; idx += 1024) {
        int kk = idx >> 4, c = idx & 15;
        wsT[c * 132 + kk] = W1[idx];
    }
    __syncthreads();
    const int s = k * CAPB, e = s + gcur[k];
    for (int i = s + t; i < e; i += 1024) atomicAdd(&h[ebuf[i] >> 17], 1);
    __syncthreads();
    if (t < BSZ) sc[t] = h[t];
    __syncthreads();
    for (int d = 1; d < BSZ; d <<= 1) {
        int add = (t < BSZ && t >= d) ? sc[t - d] : 0;
        __syncthreads();
        if (t < BSZ) sc[t] += add;
        __syncthreads();
    }
    if (t < BSZ) {
        cur[t] = sc[t] - h[t];             // exclusive scan
        const int v = (k << BSH) + t;
        if (v < N) {
            dinv[v] = rsqrtf((float)h[t] + 1.0f);
            start[v] = s + cur[t];
        }
    }
    __syncthreads();
    for (int i = s + t; i < e; i += 1024) {
        unsigned int w = ebuf[i];
        int p = atomicAdd(&cur[w >> 17], 1);
        ebuf2[s + p] = w;
    }
    // ---- fused GEMM1: node u = t>>1, K half = t&1 (h[] stable: only cur[]
    //      is mutated after the histogram barrier) ----
    const int u = t >> 1, half = t & 1;
    const int v = (k << BSH) + u;
    if (v >= N) return;
    const float dv = rsqrtf((float)h[u] + 1.0f);
    const float4* xr = (const float4*)(x + (size_t)v * 128) + half * 16;
    float acc[16];
    #pragma unroll
    for (int c = 0; c < 16; ++c) acc[c] = 0.f;
    const int kbase = half * 16;
    #pragma unroll 8
    for (int k4 = 0; k4 < 16; ++k4) {
        float4 a = xr[k4];
        #pragma unroll
        for (int c = 0; c < 16; ++c) {
            const float4 w = *(const float4*)&wsT[c * 132 + (kbase + k4) * 4];
            acc[c] = fmaf(a.x, w.x, fmaf(a.y, w.y, fmaf(a.z, w.z, fmaf(a.w, w.w, acc[c]))));
        }
    }
    #pragma unroll
    for (int c = 0; c < 16; ++c) acc[c] += __shfl_xor(acc[c], 1);
    union { __half h8[8]; uint4 u4; } o;
    #pragma unroll
    for (int c = 0; c < 8; ++c) o.h8[c] = __float2half(acc[half * 8 + c] * dv);
    ((uint4*)(ts + (size_t)v * 16))[half] = o.u4;   // even lane: ch0-7, odd: ch8-15
}

// ---- Layer-1 aggregation: 8 lanes/node, 8-deep unrolled CSR gather (no NT),
//      fused bias/ReLU + 16x16 W2 via width-8 shuffles (R11-proven) ----
__global__ __launch_bounds__(256) void pGat1(
    const unsigned int* __restrict__ ebuf2, const int* __restrict__ start,
    const int* __restrict__ gcur,
    const __half2* __restrict__ tsv, const float* __restrict__ dinv,
    const float* __restrict__ b1, const float* __restrict__ W2,
    __half2* __restrict__ ts2v, int N) {
    __shared__ float w2s[256];
    const int tid = threadIdx.x;
    w2s[tid] = W2[tid];
    __syncthreads();
    const int l = tid & 7;                 // channel pair: c0=2l, c1=2l+1
    const int v = blockIdx.x * 32 + (tid >> 3);
    if (v >= N) return;
    const int s = start[v];
    const int k = v >> BSH;
    const bool lastv = (((v + 1) & (BSZ - 1)) == 0) || (v + 1 >= N);
    const int e = lastv ? (k * CAPB + gcur[k]) : start[v + 1];
    float sx = 0.f, sy = 0.f;
    int i = s;
    for (; i + 8 <= e; i += 8) {
        unsigned int w0 = ebuf2[i],     w1 = ebuf2[i + 1];
        unsigned int w2 = ebuf2[i + 2], w3 = ebuf2[i + 3];
        unsigned int w4 = ebuf2[i + 4], w5 = ebuf2[i + 5];
        unsigned int w6 = ebuf2[i + 6], w7 = ebuf2[i + 7];
        float2 f0 = __half22float2(tsv[(size_t)(w0 & 0x1FFFF) * 8 + l]);
        float2 f1 = __half22float2(tsv[(size_t)(w1 & 0x1FFFF) * 8 + l]);
        float2 f2 = __half22float2(tsv[(size_t)(w2 & 0x1FFFF) * 8 + l]);
        float2 f3 = __half22float2(tsv[(size_t)(w3 & 0x1FFFF) * 8 + l]);
        float2 f4 = __half22float2(tsv[(size_t)(w4 & 0x1FFFF) * 8 + l]);
        float2 f5 = __half22float2(tsv[(size_t)(w5 & 0x1FFFF) * 8 + l]);
        float2 f6 = __half22float2(tsv[(size_t)(w6 & 0x1FFFF) * 8 + l]);
        float2 f7 = __half22float2(tsv[(size_t)(w7 & 0x1FFFF) * 8 + l]);
        sx += ((f0.x + f1.x) + (f2.x + f3.x)) + ((f4.x + f5.x) + (f6.x + f7.x));
        sy += ((f0.y + f1.y) + (f2.y + f3.y)) + ((f4.y + f5.y) + (f6.y + f7.y));
    }
    for (; i + 4 <= e; i += 4) {
        unsigned int w0 = ebuf2[i],     w1 = ebuf2[i + 1];
        unsigned int w2 = ebuf2[i + 2], w3 = ebuf2[i + 3];
        float2 f0 = __half22float2(tsv[(size_t)(w0 & 0x1FFFF) * 8 + l]);
        float2 f1 = __half22float2(tsv[(size_t)(w1 & 0x1FFFF) * 8 + l]);
        float2 f2 = __half22float2(tsv[(size_t)(w2 & 0x1FFFF) * 8 + l]);
        float2 f3 = __half22float2(tsv[(size_t)(w3 & 0x1FFFF) * 8 + l]);
        sx += (f0.x + f1.x) + (f2.x + f3.x);
        sy += (f0.y + f1.y) + (f2.y + f3.y);
    }
    for (; i < e; ++i) {
        unsigned int w = ebuf2[i];
        float2 f = __half22float2(tsv[(size_t)(w & 0x1FFFF) * 8 + l]);
        sx += f.x; sy += f.y;
    }
    const float dv = dinv[v];
    float2 sf = __half22float2(tsv[(size_t)v * 8 + l]);
    float hx = fmaxf(dv * (sx + sf.x) + b1[2 * l],     0.f);
    float hy = fmaxf(dv * (sy + sf.y) + b1[2 * l + 1], 0.f);
    float ox = 0.f, oy = 0.f;
    #pragma unroll
    for (int j = 0; j < 8; ++j) {
        float ax = __shfl(hx, j, 8);       // channel 2j
        float ay = __shfl(hy, j, 8);       // channel 2j+1
        ox = fmaf(ax, w2s[(2 * j) * 16 + 2 * l],     fmaf(ay, w2s[(2 * j + 1) * 16 + 2 * l],     ox));
        oy = fmaf(ax, w2s[(2 * j) * 16 + 2 * l + 1], fmaf(ay, w2s[(2 * j + 1) * 16 + 2 * l + 1], oy));
    }
    ts2v[(size_t)v * 8 + l] = __halves2half2(__float2half(dv * ox), __float2half(dv * oy));
}

// ---- Layer-2 aggregation: 8 lanes/node, 8-deep unrolled CSR gather + bias ----
__global__ __launch_bounds__(256) void pGat2(
    const unsigned int* __restrict__ ebuf2, const int* __restrict__ start,
    const int* __restrict__ gcur,
    const __half2* __restrict__ tsv, const float* __restrict__ dinv,
    const float* __restrict__ b2, __half2* __restrict__ h2v, int N) {
    const int tid = threadIdx.x;
    const int l = tid & 7;
    const int v = blockIdx.x * 32 + (tid >> 3);
    if (v >= N) return;
    const int s = start[v];
    const int k = v >> BSH;
    const bool lastv = (((v + 1) & (BSZ - 1)) == 0) || (v + 1 >= N);
    const int e = lastv ? (k * CAPB + gcur[k]) : start[v + 1];
    float sx = 0.f, sy = 0.f;
    int i = s;
    for (; i + 8 <= e; i += 8) {
        unsigned int w0 = ebuf2[i],     w1 = ebuf2[i + 1];
        unsigned int w2 = ebuf2[i + 2], w3 = ebuf2[i + 3];
        unsigned int w4 = ebuf2[i + 4], w5 = ebuf2[i + 5];
        unsigned int w6 = ebuf2[i + 6], w7 = ebuf2[i + 7];
        float2 f0 = __half22float2(tsv[(size_t)(w0 & 0x1FFFF) * 8 + l]);
        float2 f1 = __half22float2(tsv[(size_t)(w1 & 0x1FFFF) * 8 + l]);
        float2 f2 = __half22float2(tsv[(size_t)(w2 & 0x1FFFF) * 8 + l]);
        float2 f3 = __half22float2(tsv[(size_t)(w3 & 0x1FFFF) * 8 + l]);
        float2 f4 = __half22float2(tsv[(size_t)(w4 & 0x1FFFF) * 8 + l]);
        float2 f5 = __half22float2(tsv[(size_t)(w5 & 0x1FFFF) * 8 + l]);
        float2 f6 = __half22float2(tsv[(size_t)(w6 & 0x1FFFF) * 8 + l]);
        float2 f7 = __half22float2(tsv[(size_t)(w7 & 0x1FFFF) * 8 + l]);
        sx += ((f0.x + f1.x) + (f2.x + f3.x)) + ((f4.x + f5.x) + (f6.x + f7.x));
        sy += ((f0.y + f1.y) + (f2.y + f3.y)) + ((f4.y + f5.y) + (f6.y + f7.y));
    }
    for (; i + 4 <= e; i += 4) {
        unsigned int w0 = ebuf2[i],     w1 = ebuf2[i + 1];
        unsigned int w2 = ebuf2[i + 2], w3 = ebuf2[i + 3];
        float2 f0 = __half22float2(tsv[(size_t)(w0 & 0x1FFFF) * 8 + l]);
        float2 f1 = __half22float2(tsv[(size_t)(w1 & 0x1FFFF) * 8 + l]);
        float2 f2 = __half22float2(tsv[(size_t)(w2 & 0x1FFFF) * 8 + l]);
        float2 f3 = __half22float2(tsv[(size_t)(w3 & 0x1FFFF) * 8 + l]);
        sx += (f0.x + f1.x) + (f2.x + f3.x);
        sy += (f0.y + f1.y) + (f2.y + f3.y);
    }
    for (; i < e; ++i) {
        unsigned int w = ebuf2[i];
        float2 f = __half22float2(tsv[(size_t)(w & 0x1FFFF) * 8 + l]);
        sx += f.x; sy += f.y;
    }
    float2 sf = __half22float2(tsv[(size_t)v * 8 + l]);
    const float dv = dinv[v];
    h2v[(size_t)v * 8 + l] = __halves2half2(
        __float2half(dv * (sx + sf.x) + b2[2 * l]),
        __float2half(dv * (sy + sf.y) + b2[2 * l + 1]));
}

// ---- Edge scores (R8/R10-proven: 1 edge/thread, no NT) ----
__global__ void k_score(const int* __restrict__ row, const int* __restrict__ col,
                        const __half* __restrict__ h2h, float* __restrict__ out, int E) {
    int e = blockIdx.x * 256 + threadIdx.x;
    if (e < E) {
        union { uint4 u[2]; __half2 h[8]; } a, b;
        const uint4* pa = (const uint4*)(h2h + (size_t)row[e] * 16);
        const uint4* pb = (const uint4*)(h2h + (size_t)col[e] * 16);
        a.u[0] = pa[0]; a.u[1] = pa[1];
        b.u[0] = pb[0]; b.u[1] = pb[1];
        float d = 0.f;
        #pragma unroll
        for (int i = 0; i < 8; ++i) {
            float2 fa = __half22float2(a.h[i]);
            float2 fb = __half22float2(b.h[i]);
            d = fmaf(fa.x, fb.x, fmaf(fa.y, fb.y, d));
        }
        out[e] = 1.0f / (1.0f + __expf(-d));
    }
}

// ---------------- Fallback (R2 atomic path) ----------------
__global__ void k_countf(const int* __restrict__ col, float* __restrict__ deg, int E) {
    int e = blockIdx.x * 256 + threadIdx.x;
    if (e < E) atomicAdd(&deg[col[e]], 1.0f);
}
__global__ void k_dinvf(float* __restrict__ dinv, int N) {
    int v = blockIdx.x * 256 + threadIdx.x;
    if (v < N) dinv[v] = rsqrtf(dinv[v] + 1.0f);
}
__global__ __launch_bounds__(256) void k_gemm1f(
    const float* __restrict__ x, const float* __restrict__ W1,
    const float* __restrict__ dinv, float* __restrict__ ts, int N) {
    __shared__ float wsT[16 * 132];
    const int tid = threadIdx.x;
    for (int idx = tid; idx < 2048; idx += 256) {
        int k = idx >> 4, c = idx & 15;
        wsT[c * 132 + k] = W1[idx];
    }
    __syncthreads();
    const int n = blockIdx.x * 256 + tid;
    if (n >= N) return;
    const float4* xr = (const float4*)(x + (size_t)n * 128);
    float acc[16];
    #pragma unroll
    for (int c = 0; c < 16; ++c) acc[c] = 0.f;
    for (int k4 = 0; k4 < 32; ++k4) {
        float4 a = xr[k4];
        #pragma unroll
        for (int c = 0; c < 16; ++c) {
            const float4 w = *(const float4*)&wsT[c * 132 + k4 * 4];
            acc[c] = fmaf(a.x, w.x, fmaf(a.y, w.y, fmaf(a.z, w.z, fmaf(a.w, w.w, acc[c]))));
        }
    }
    float dv = dinv[n];
    float4* o = (float4*)(ts + (size_t)n * 16);
    #pragma unroll
    for (int q = 0; q < 4; ++q)
        o[q] = make_float4(acc[4*q] * dv, acc[4*q+1] * dv, acc[4*q+2] * dv, acc[4*q+3] * dv);
}
__global__ void k_scatter(const int* __restrict__ row, const int* __restrict__ col,
                          const float* __restrict__ ts, float* __restrict__ acc, int E) {
    int g = blockIdx.x * 256 + threadIdx.x;
    int e = g >> 4, c = g & 15;
    if (e < E) atomicAdd(&acc[(size_t)col[e] * 16 + c], ts[(size_t)row[e] * 16 + c]);
}
__global__ void k_finalize(float* __restrict__ acc, const float* __restrict__ ts,
                           const float* __restrict__ dinv, const float* __restrict__ b,
                           int N, int relu) {
    int g = blockIdx.x * 256 + threadIdx.x;
    int v = g >> 4, c = g & 15;
    if (v < N) {
        float h = dinv[v] * (acc[g] + ts[g]) + b[c];
        if (relu) h = fmaxf(h, 0.f);
        acc[g] = h;
    }
}
__global__ __launch_bounds__(256) void k_gemm2f(
    const float* __restrict__ h1, const float* __restrict__ W2,
    const float* __restrict__ dinv, float* __restrict__ ts2, int N) {
    __shared__ float hs[16 * 17];
    __shared__ float ws2[256];
    const int tid = threadIdx.x;
    const int base = blockIdx.x * 16;
    if (tid < 64) ((float4*)ws2)[tid] = ((const float4*)W2)[tid];
    if (tid >= 64 && tid < 128) {
        int t2 = tid - 64;
        float4 v4 = ((const float4*)(h1 + (size_t)base * 16))[t2];
        float* d = &hs[(t2 >> 2) * 17 + (t2 & 3) * 4];
        d[0] = v4.x; d[1] = v4.y; d[2] = v4.z; d[3] = v4.w;
    }
    __syncthreads();
    const int r = tid >> 4, c = tid & 15;
    float a = 0.f;
    #pragma unroll
    for (int kk = 0; kk < 16; ++kk) a = fmaf(hs[r * 17 + kk], ws2[kk * 16 + c], a);
    ts2[(size_t)(base + r) * 16 + c] = a * dinv[base + r];
}
__global__ void k_scoref(const int* __restrict__ row, const int* __restrict__ col,
                         const float* __restrict__ h2, float* __restrict__ out, int E) {
    int e = blockIdx.x * 256 + threadIdx.x;
    if (e < E) {
        const float4* a = (const float4*)(h2 + (size_t)row[e] * 16);
        const float4* b = (const float4*)(h2 + (size_t)col[e] * 16);
        float d = 0.f;
        #pragma unroll
        for (int i = 0; i < 4; ++i) {
            float4 u = a[i], v = b[i];
            d += u.x * v.x + u.y * v.y + u.z * v.z + u.w * v.w;
        }
        out[e] = 1.0f / (1.0f + __expf(-d));
    }
}

extern "C" void kernel_launch(void* const* d_in, const int* in_sizes, int n_in,
                              void* d_out, int out_size, void* d_ws, size_t ws_size,
                              hipStream_t stream) {
    const float* x  = (const float*)d_in[0];
    const int*   ei = (const int*)d_in[1];
    const float* W1 = (const float*)d_in[2];
    const float* b1 = (const float*)d_in[3];
    const float* W2 = (const float*)d_in[4];
    const float* b2 = (const float*)d_in[5];

    const int N = in_sizes[0] / 128;   // 100000
    const int E = in_sizes[1] / 2;     // 3200000
    const int* row = ei;
    const int* col = ei + E;
    float* out = (float*)d_out;

    const int NBUK = (N + BSZ - 1) / BSZ;          // 196
    const int CN = (E + MAXCH - 1) / MAXCH;        // 1000 chunks
    const int CH = MAXCH;                          // 3200, multiple of 4

    char* ws = (char*)d_ws;
    size_t off = 0;
    auto alloc = [&](size_t bytes) { void* p = ws + off; off += (bytes + 255) & ~(size_t)255; return p; };
    float*  dinv  = (float*)alloc((size_t)N * 4);
    __half* ts1h  = (__half*)alloc((size_t)N * 32);    // also h2h after pGat1
    __half* ts2h  = (__half*)alloc((size_t)N * 32);
    int*    start = (int*)alloc((size_t)(N + 1) * 4);
    int*    gcur  = (int*)alloc((size_t)NBUK * 4);
    unsigned int* ebuf  = (unsigned int*)alloc((size_t)NBUK * CAPB * 4);   // 25.7 MB
    unsigned int* ebuf2 = (unsigned int*)alloc((size_t)NBUK * CAPB * 4);   // 25.7 MB
    const size_t need = off;    // ~59 MB at N=100k, E=3.2M

    // fixed-capacity guard: uniform input fills buckets to ~CAPB/2 (+-128 sigma)
    if (N <= 131072 && NBUK <= 256 && CN <= MAXCHUNKS &&
        (size_t)E * 2 <= (size_t)NBUK * CAPB && ws_size >= need) {
        hipMemsetAsync(gcur, 0, (size_t)NBUK * 4, stream);
        pSort<<<CN, 512, 0, stream>>>(row, col, gcur, ebuf, E, CH, NBUK);
        pS2G<<<NBUK, 1024, 0, stream>>>(ebuf, gcur, x, W1, ebuf2, dinv, start, ts1h, N);
        pGat1<<<(N + 31) / 32, 256, 0, stream>>>(ebuf2, start, gcur, (const __half2*)ts1h,
                                                 dinv, b1, W2, (__half2*)ts2h, N);
        __half* h2h = ts1h;   // ts1h dead after pGat1
        pGat2<<<(N + 31) / 32, 256, 0, stream>>>(ebuf2, start, gcur, (const __half2*)ts2h,
                                                 dinv, b2, (__half2*)h2h, N);
        k_score<<<(E + 255) / 256, 256, 0, stream>>>(row, col, h2h, out, E);
    } else {
        // R2 fallback, fp32 buffers carved independently
        float* dinvF = (float*)ws;
        float* ts1F  = (float*)(ws + (size_t)N * 4);
        float* ts2F  = (float*)(ws + (size_t)N * 4 + (size_t)N * 64);
        hipMemsetAsync(dinvF, 0, (size_t)N * 4, stream);
        hipMemsetAsync(ts2F, 0, (size_t)N * 64, stream);
        k_countf<<<(E + 255) / 256, 256, 0, stream>>>(col, dinvF, E);
        k_dinvf<<<(N + 255) / 256, 256, 0, stream>>>(dinvF, N);
        k_gemm1f<<<(N + 255) / 256, 256, 0, stream>>>(x, W1, dinvF, ts1F, N);
        k_scatter<<<(E * 16) / 256, 256, 0, stream>>>(row, col, ts1F, ts2F, E);
        k_finalize<<<(N * 16 + 255) / 256, 256, 0, stream>>>(ts2F, ts1F, dinvF, b1, N, 1);
        k_gemm2f<<<N / 16, 256, 0, stream>>>(ts2F, W2, dinvF, ts1F, N);
        hipMemsetAsync(ts2F, 0, (size_t)N * 64, stream);
        k_scatter<<<(E * 16) / 256, 256, 0, stream>>>(row, col, ts1F, ts2F, E);
        k_finalize<<<(N * 16 + 255) / 256, 256, 0, stream>>>(ts2F, ts1F, dinvF, b2, N, 0);
        k_scoref<<<(E + 255) / 256, 256, 0, stream>>>(row, col, ts2F, out, E);
    }
}

// Round 7
// 256.603 us; speedup vs baseline: 1.0088x; 1.0088x over previous
//
#include <hip/hip_runtime.h>
#include <hip/hip_bf16.h>
#include <hip/hip_fp16.h>
#include <math.h>

// GCN link prediction. R18 = R17 structure with the bucket-grained kernels
// de-starved: BSZ 512->128 (NBUK 196->782) so pS2G launches 782 blocks
// (~3/CU, occupancy 25%->~75%; R17 counters showed 196 blocks < 256 CUs was
// the latency bottleneck). pS2G also register-caches its edges between the
// histogram and scatter passes (deletes the 2nd 25.6MB ebuf read) and the
// fused gemm uses an interleaved 4-thread K-split (coalesced x, conflict-free
// wsT banks). pSort is the R14-proven 1024-wide chunk sort with the R16
// atomic base grab (no scan pipeline).
//   deg[v] = incount(col==v)+1 ; dinv = rsqrt(deg)
//   ts[v]  = (h[v]@W)*dinv[v]          (fp16 gather tables, L2-resident)
//   h'[c]  = act(dinv[c]*(sum_{e:col=c} ts[row_e] + ts[c]) + b)
//   score  = sigmoid(dot(h2[row], h2[col]))

#define BSH 7
#define BSZ 128            // nodes per bucket -> NBUK = 782 (<= 1024)
#define CAPB 8192          // slots per bucket (2x avg 4092; +60 sigma)
#define RCAP 12            // edge register cache per thread in pS2G (512 thr)
#define MAXCH 3200         // edges per chunk (multiple of 4)
#define MAXCHUNKS 1024

// ---- pSort: chunk histogram -> atomic base grab -> LDS bucket-order ->
//      run writes into fixed-capacity bucket regions ----
__global__ __launch_bounds__(1024) void pSort(
    const int* __restrict__ row, const int* __restrict__ col,
    int* __restrict__ gcur, unsigned int* __restrict__ ebuf,
    int E, int CH, int NBUK) {
    __shared__ unsigned int se[MAXCH];        // chunk edges, bucket-ordered
    __shared__ unsigned short pk[MAXCH];      // bucket id per LDS slot
    __shared__ int lhist[1024], lbase[1024], lcur[1024], gbase[1024];
    const int t = threadIdx.x, b = blockIdx.x;
    lhist[t] = 0;
    __syncthreads();
    const int s = b * CH, e = min(E, s + CH);
    const int cnt = e - s;
    const int n4 = cnt >> 2;
    const int4* c4 = (const int4*)(col + s);
    const int4* r4 = (const int4*)(row + s);
    for (int i = t; i < n4; i += 1024) {
        int4 c = c4[i];
        atomicAdd(&lhist[c.x >> BSH], 1);
        atomicAdd(&lhist[c.y >> BSH], 1);
        atomicAdd(&lhist[c.z >> BSH], 1);
        atomicAdd(&lhist[c.w >> BSH], 1);
    }
    for (int i = (n4 << 2) + t; i < cnt; i += 1024) atomicAdd(&lhist[col[s + i] >> BSH], 1);
    __syncthreads();
    {   // 1024-wide exclusive scan of lhist -> lbase (scratch in lcur)
        int own = lhist[t];
        lcur[t] = own;
        __syncthreads();
        for (int d = 1; d < 1024; d <<= 1) {
            int add = (t >= d) ? lcur[t - d] : 0;
            __syncthreads();
            lcur[t] += add;
            __syncthreads();
        }
        lbase[t] = lcur[t] - own;
        lcur[t] = lbase[t];
        __syncthreads();
        if (t < NBUK) {   // grab this chunk's range in bucket t
            int base = atomicAdd(&gcur[t], lhist[t]);
            gbase[t] = t * CAPB + base - lbase[t];
        }
    }
    __syncthreads();
    // placement into LDS (bucket-ordered)
    for (int i = t; i < n4; i += 1024) {
        int4 c = c4[i];
        int4 r = r4[i];
        int k0 = c.x >> BSH, p0 = atomicAdd(&lcur[k0], 1);
        se[p0] = ((unsigned int)(c.x & (BSZ - 1)) << 17) | (unsigned int)r.x; pk[p0] = (unsigned short)k0;
        int k1 = c.y >> BSH, p1 = atomicAdd(&lcur[k1], 1);
        se[p1] = ((unsigned int)(c.y & (BSZ - 1)) << 17) | (unsigned int)r.y; pk[p1] = (unsigned short)k1;
        int k2 = c.z >> BSH, p2 = atomicAdd(&lcur[k2], 1);
        se[p2] = ((unsigned int)(c.z & (BSZ - 1)) << 17) | (unsigned int)r.z; pk[p2] = (unsigned short)k2;
        int k3 = c.w >> BSH, p3 = atomicAdd(&lcur[k3], 1);
        se[p3] = ((unsigned int)(c.w & (BSZ - 1)) << 17) | (unsigned int)r.w; pk[p3] = (unsigned short)k3;
    }
    for (int i = (n4 << 2) + t; i < cnt; i += 1024) {
        int c = col[s + i], r = row[s + i];
        int k = c >> BSH, p = atomicAdd(&lcur[k], 1);
        se[p] = ((unsigned int)(c & (BSZ - 1)) << 17) | (unsigned int)r; pk[p] = (unsigned short)k;
    }
    __syncthreads();
    // write-out: consecutive LDS slots in a bucket -> consecutive global
    for (int i = t; i < cnt; i += 1024) {
        int k = pk[i];
        ebuf[gbase[k] + i] = se[i];
    }
}

// ---- pS2G: in-bucket counting sort (emits dinv + CSR start) with edge
//      register cache + fused GEMM1 (4 threads/node, interleaved K) ----
__global__ __launch_bounds__(512) void pS2G(
    const unsigned int* __restrict__ ebuf, const int* __restrict__ gcur,
    const float* __restrict__ x, const float* __restrict__ W1,
    unsigned int* __restrict__ ebuf2, float* __restrict__ dinv,
    int* __restrict__ start, __half* __restrict__ ts, int N) {
    __shared__ int h[BSZ], sc[BSZ], cur[BSZ];
    __shared__ float wsT[16 * 132];
    const int t = threadIdx.x, k = blockIdx.x;
    if (t < BSZ) h[t] = 0;
    // stage W1 transposed: wsT[c*132+kk] = W1[kk*16+c]
    for (int idx = t; idx < 2048; idx += 512) {
        int kk = idx >> 4, c = idx & 15;
        wsT[c * 132 + kk] = W1[idx];
    }
    __syncthreads();
    const int s = k * CAPB, e = s + gcur[k];
    const int cnt = e - s;
    unsigned int r[RCAP];
    const bool fits = (cnt <= 512 * RCAP);
    if (fits) {
        int nr = 0;
        for (int i = s + t; i < e; i += 512) {
            unsigned int w = ebuf[i];
            r[nr++] = w;
            atomicAdd(&h[w >> 17], 1);
        }
    } else {
        for (int i = s + t; i < e; i += 512) atomicAdd(&h[ebuf[i] >> 17], 1);
    }
    __syncthreads();
    if (t < BSZ) sc[t] = h[t];
    __syncthreads();
    for (int d = 1; d < BSZ; d <<= 1) {
        int add = (t < BSZ && t >= d) ? sc[t - d] : 0;
        __syncthreads();
        if (t < BSZ) sc[t] += add;
        __syncthreads();
    }
    if (t < BSZ) {
        cur[t] = sc[t] - h[t];             // exclusive scan
        const int v = (k << BSH) + t;
        if (v < N) {
            dinv[v] = rsqrtf((float)h[t] + 1.0f);
            start[v] = s + cur[t];
        }
    }
    __syncthreads();
    if (fits) {
        int nr = 0;
        for (int i = s + t; i < e; i += 512) {
            unsigned int w = r[nr++];
            int p = atomicAdd(&cur[w >> 17], 1);
            ebuf2[s + p] = w;
        }
    } else {
        for (int i = s + t; i < e; i += 512) {
            unsigned int w = ebuf[i];
            int p = atomicAdd(&cur[w >> 17], 1);
            ebuf2[s + p] = w;
        }
    }
    // ---- fused GEMM1: node u = t>>2, K-slice q = t&3 interleaved (k = q+4*k4)
    //      h[] is stable after the histogram barrier (only cur[] mutates) ----
    const int u = t >> 2, q = t & 3;
    const int v = (k << BSH) + u;
    if (v >= N) return;
    const float dv = rsqrtf((float)h[u] + 1.0f);
    const float4* xr = (const float4*)(x + (size_t)v * 128);
    float acc[16];
    #pragma unroll
    for (int c = 0; c < 16; ++c) acc[c] = 0.f;
    #pragma unroll
    for (int k4 = 0; k4 < 8; ++k4) {
        const int kk = q + 4 * k4;         // float4 index in [0,32)
        float4 a = xr[kk];
        #pragma unroll
        for (int c = 0; c < 16; ++c) {
            const float4 w = *(const float4*)&wsT[c * 132 + kk * 4];
            acc[c] = fmaf(a.x, w.x, fmaf(a.y, w.y, fmaf(a.z, w.z, fmaf(a.w, w.w, acc[c]))));
        }
    }
    #pragma unroll
    for (int c = 0; c < 16; ++c) {
        acc[c] += __shfl_xor(acc[c], 1);
        acc[c] += __shfl_xor(acc[c], 2);
    }
    union { __half h4[4]; uint2 u2; } o;
    #pragma unroll
    for (int c = 0; c < 4; ++c) o.h4[c] = __float2half(acc[q * 4 + c] * dv);
    ((uint2*)(ts + (size_t)v * 16))[q] = o.u2;   // q lanes write 8B each, 32B/node
}

// ---- Layer-1 aggregation: 8 lanes/node, 8-deep unrolled CSR gather (no NT),
//      fused bias/ReLU + 16x16 W2 via width-8 shuffles (R11-proven) ----
__global__ __launch_bounds__(256) void pGat1(
    const unsigned int* __restrict__ ebuf2, const int* __restrict__ start,
    const int* __restrict__ gcur,
    const __half2* __restrict__ tsv, const float* __restrict__ dinv,
    const float* __restrict__ b1, const float* __restrict__ W2,
    __half2* __restrict__ ts2v, int N) {
    __shared__ float w2s[256];
    const int tid = threadIdx.x;
    w2s[tid] = W2[tid];
    __syncthreads();
    const int l = tid & 7;                 // channel pair: c0=2l, c1=2l+1
    const int v = blockIdx.x * 32 + (tid >> 3);
    if (v >= N) return;
    const int s = start[v];
    const int k = v >> BSH;
    const bool lastv = (((v + 1) & (BSZ - 1)) == 0) || (v + 1 >= N);
    const int e = lastv ? (k * CAPB + gcur[k]) : start[v + 1];
    float sx = 0.f, sy = 0.f;
    int i = s;
    for (; i + 8 <= e; i += 8) {
        unsigned int w0 = ebuf2[i],     w1 = ebuf2[i + 1];
        unsigned int w2 = ebuf2[i + 2], w3 = ebuf2[i + 3];
        unsigned int w4 = ebuf2[i + 4], w5 = ebuf2[i + 5];
        unsigned int w6 = ebuf2[i + 6], w7 = ebuf2[i + 7];
        float2 f0 = __half22float2(tsv[(size_t)(w0 & 0x1FFFF) * 8 + l]);
        float2 f1 = __half22float2(tsv[(size_t)(w1 & 0x1FFFF) * 8 + l]);
        float2 f2 = __half22float2(tsv[(size_t)(w2 & 0x1FFFF) * 8 + l]);
        float2 f3 = __half22float2(tsv[(size_t)(w3 & 0x1FFFF) * 8 + l]);
        float2 f4 = __half22float2(tsv[(size_t)(w4 & 0x1FFFF) * 8 + l]);
        float2 f5 = __half22float2(tsv[(size_t)(w5 & 0x1FFFF) * 8 + l]);
        float2 f6 = __half22float2(tsv[(size_t)(w6 & 0x1FFFF) * 8 + l]);
        float2 f7 = __half22float2(tsv[(size_t)(w7 & 0x1FFFF) * 8 + l]);
        sx += ((f0.x + f1.x) + (f2.x + f3.x)) + ((f4.x + f5.x) + (f6.x + f7.x));
        sy += ((f0.y + f1.y) + (f2.y + f3.y)) + ((f4.y + f5.y) + (f6.y + f7.y));
    }
    for (; i + 4 <= e; i += 4) {
        unsigned int w0 = ebuf2[i],     w1 = ebuf2[i + 1];
        unsigned int w2 = ebuf2[i + 2], w3 = ebuf2[i + 3];
        float2 f0 = __half22float2(tsv[(size_t)(w0 & 0x1FFFF) * 8 + l]);
        float2 f1 = __half22float2(tsv[(size_t)(w1 & 0x1FFFF) * 8 + l]);
        float2 f2 = __half22float2(tsv[(size_t)(w2 & 0x1FFFF) * 8 + l]);
        float2 f3 = __half22float2(tsv[(size_t)(w3 & 0x1FFFF) * 8 + l]);
        sx += (f0.x + f1.x) + (f2.x + f3.x);
        sy += (f0.y + f1.y) + (f2.y + f3.y);
    }
    for (; i < e; ++i) {
        unsigned int w = ebuf2[i];
        float2 f = __half22float2(tsv[(size_t)(w & 0x1FFFF) * 8 + l]);
        sx += f.x; sy += f.y;
    }
    const float dv = dinv[v];
    float2 sf = __half22float2(tsv[(size_t)v * 8 + l]);
    float hx = fmaxf(dv * (sx + sf.x) + b1[2 * l],     0.f);
    float hy = fmaxf(dv * (sy + sf.y) + b1[2 * l + 1], 0.f);
    float ox = 0.f, oy = 0.f;
    #pragma unroll
    for (int j = 0; j < 8; ++j) {
        float ax = __shfl(hx, j, 8);       // channel 2j
        float ay = __shfl(hy, j, 8);       // channel 2j+1
        ox = fmaf(ax, w2s[(2 * j) * 16 + 2 * l],     fmaf(ay, w2s[(2 * j + 1) * 16 + 2 * l],     ox));
        oy = fmaf(ax, w2s[(2 * j) * 16 + 2 * l + 1], fmaf(ay, w2s[(2 * j + 1) * 16 + 2 * l + 1], oy));
    }
    ts2v[(size_t)v * 8 + l] = __halves2half2(__float2half(dv * ox), __float2half(dv * oy));
}

// ---- Layer-2 aggregation: 8 lanes/node, 8-deep unrolled CSR gather + bias ----
__global__ __launch_bounds__(256) void pGat2(
    const unsigned int* __restrict__ ebuf2, const int* __restrict__ start,
    const int* __restrict__ gcur,
    const __half2* __restrict__ tsv, const float* __restrict__ dinv,
    const float* __restrict__ b2, __half2* __restrict__ h2v, int N) {
    const int tid = threadIdx.x;
    const int l = tid & 7;
    const int v = blockIdx.x * 32 + (tid >> 3);
    if (v >= N) return;
    const int s = start[v];
    const int k = v >> BSH;
    const bool lastv = (((v + 1) & (BSZ - 1)) == 0) || (v + 1 >= N);
    const int e = lastv ? (k * CAPB + gcur[k]) : start[v + 1];
    float sx = 0.f, sy = 0.f;
    int i = s;
    for (; i + 8 <= e; i += 8) {
        unsigned int w0 = ebuf2[i],     w1 = ebuf2[i + 1];
        unsigned int w2 = ebuf2[i + 2], w3 = ebuf2[i + 3];
        unsigned int w4 = ebuf2[i + 4], w5 = ebuf2[i + 5];
        unsigned int w6 = ebuf2[i + 6], w7 = ebuf2[i + 7];
        float2 f0 = __half22float2(tsv[(size_t)(w0 & 0x1FFFF) * 8 + l]);
        float2 f1 = __half22float2(tsv[(size_t)(w1 & 0x1FFFF) * 8 + l]);
        float2 f2 = __half22float2(tsv[(size_t)(w2 & 0x1FFFF) * 8 + l]);
        float2 f3 = __half22float2(tsv[(size_t)(w3 & 0x1FFFF) * 8 + l]);
        float2 f4 = __half22float2(tsv[(size_t)(w4 & 0x1FFFF) * 8 + l]);
        float2 f5 = __half22float2(tsv[(size_t)(w5 & 0x1FFFF) * 8 + l]);
        float2 f6 = __half22float2(tsv[(size_t)(w6 & 0x1FFFF) * 8 + l]);
        float2 f7 = __half22float2(tsv[(size_t)(w7 & 0x1FFFF) * 8 + l]);
        sx += ((f0.x + f1.x) + (f2.x + f3.x)) + ((f4.x + f5.x) + (f6.x + f7.x));
        sy += ((f0.y + f1.y) + (f2.y + f3.y)) + ((f4.y + f5.y) + (f6.y + f7.y));
    }
    for (; i + 4 <= e; i += 4) {
        unsigned int w0 = ebuf2[i],     w1 = ebuf2[i + 1];
        unsigned int w2 = ebuf2[i + 2], w3 = ebuf2[i + 3];
        float2 f0 = __half22float2(tsv[(size_t)(w0 & 0x1FFFF) * 8 + l]);
        float2 f1 = __half22float2(tsv[(size_t)(w1 & 0x1FFFF) * 8 + l]);
        float2 f2 = __half22float2(tsv[(size_t)(w2 & 0x1FFFF) * 8 + l]);
        float2 f3 = __half22float2(tsv[(size_t)(w3 & 0x1FFFF) * 8 + l]);
        sx += (f0.x + f1.x) + (f2.x + f3.x);
        sy += (f0.y + f1.y) + (f2.y + f3.y);
    }
    for (; i < e; ++i) {
        unsigned int w = ebuf2[i];
        float2 f = __half22float2(tsv[(size_t)(w & 0x1FFFF) * 8 + l]);
        sx += f.x; sy += f.y;
    }
    float2 sf = __half22float2(tsv[(size_t)v * 8 + l]);
    const float dv = dinv[v];
    h2v[(size_t)v * 8 + l] = __halves2half2(
        __float2half(dv * (sx + sf.x) + b2[2 * l]),
        __float2half(dv * (sy + sf.y) + b2[2 * l + 1]));
}

// ---- Edge scores (R8/R10-proven: 1 edge/thread, no NT) ----
__global__ void k_score(const int* __restrict__ row, const int* __restrict__ col,
                        const __half* __restrict__ h2h, float* __restrict__ out, int E) {
    int e = blockIdx.x * 256 + threadIdx.x;
    if (e < E) {
        union { uint4 u[2]; __half2 h[8]; } a, b;
        const uint4* pa = (const uint4*)(h2h + (size_t)row[e] * 16);
        const uint4* pb = (const uint4*)(h2h + (size_t)col[e] * 16);
        a.u[0] = pa[0]; a.u[1] = pa[1];
        b.u[0] = pb[0]; b.u[1] = pb[1];
        float d = 0.f;
        #pragma unroll
        for (int i = 0; i < 8; ++i) {
            float2 fa = __half22float2(a.h[i]);
            float2 fb = __half22float2(b.h[i]);
            d = fmaf(fa.x, fb.x, fmaf(fa.y, fb.y, d));
        }
        out[e] = 1.0f / (1.0f + __expf(-d));
    }
}

// ---------------- Fallback (R2 atomic path) ----------------
__global__ void k_countf(const int* __restrict__ col, float* __restrict__ deg, int E) {
    int e = blockIdx.x * 256 + threadIdx.x;
    if (e < E) atomicAdd(&deg[col[e]], 1.0f);
}
__global__ void k_dinvf(float* __restrict__ dinv, int N) {
    int v = blockIdx.x * 256 + threadIdx.x;
    if (v < N) dinv[v] = rsqrtf(dinv[v] + 1.0f);
}
__global__ __launch_bounds__(256) void k_gemm1f(
    const float* __restrict__ x, const float* __restrict__ W1,
    const float* __restrict__ dinv, float* __restrict__ ts, int N) {
    __shared__ float wsT[16 * 132];
    const int tid = threadIdx.x;
    for (int idx = tid; idx < 2048; idx += 256) {
        int k = idx >> 4, c = idx & 15;
        wsT[c * 132 + k] = W1[idx];
    }
    __syncthreads();
    const int n = blockIdx.x * 256 + tid;
    if (n >= N) return;
    const float4* xr = (const float4*)(x + (size_t)n * 128);
    float acc[16];
    #pragma unroll
    for (int c = 0; c < 16; ++c) acc[c] = 0.f;
    for (int k4 = 0; k4 < 32; ++k4) {
        float4 a = xr[k4];
        #pragma unroll
        for (int c = 0; c < 16; ++c) {
            const float4 w = *(const float4*)&wsT[c * 132 + k4 * 4];
            acc[c] = fmaf(a.x, w.x, fmaf(a.y, w.y, fmaf(a.z, w.z, fmaf(a.w, w.w, acc[c]))));
        }
    }
    float dv = dinv[n];
    float4* o = (float4*)(ts + (size_t)n * 16);
    #pragma unroll
    for (int q = 0; q < 4; ++q)
        o[q] = make_float4(acc[4*q] * dv, acc[4*q+1] * dv, acc[4*q+2] * dv, acc[4*q+3] * dv);
}
__global__ void k_scatter(const int* __restrict__ row, const int* __restrict__ col,
                          const float* __restrict__ ts, float* __restrict__ acc, int E) {
    int g = blockIdx.x * 256 + threadIdx.x;
    int e = g >> 4, c = g & 15;
    if (e < E) atomicAdd(&acc[(size_t)col[e] * 16 + c], ts[(size_t)row[e] * 16 + c]);
}
__global__ void k_finalize(float* __restrict__ acc, const float* __restrict__ ts,
                           const float* __restrict__ dinv, const float* __restrict__ b,
                           int N, int relu) {
    int g = blockIdx.x * 256 + threadIdx.x;
    int v = g >> 4, c = g & 15;
    if (v < N) {
        float h = dinv[v] * (acc[g] + ts[g]) + b[c];
        if (relu) h = fmaxf(h, 0.f);
        acc[g] = h;
    }
}
__global__ __launch_bounds__(256) void k_gemm2f(
    const float* __restrict__ h1, const float* __restrict__ W2,
    const float* __restrict__ dinv, float* __restrict__ ts2, int N) {
    __shared__ float hs[16 * 17];
    __shared__ float ws2[256];
    const int tid = threadIdx.x;
    const int base = blockIdx.x * 16;
    if (tid < 64) ((float4*)ws2)[tid] = ((const float4*)W2)[tid];
    if (tid >= 64 && tid < 128) {
        int t2 = tid - 64;
        float4 v4 = ((const float4*)(h1 + (size_t)base * 16))[t2];
        float* d = &hs[(t2 >> 2) * 17 + (t2 & 3) * 4];
        d[0] = v4.x; d[1] = v4.y; d[2] = v4.z; d[3] = v4.w;
    }
    __syncthreads();
    const int r = tid >> 4, c = tid & 15;
    float a = 0.f;
    #pragma unroll
    for (int kk = 0; kk < 16; ++kk) a = fmaf(hs[r * 17 + kk], ws2[kk * 16 + c], a);
    ts2[(size_t)(base + r) * 16 + c] = a * dinv[base + r];
}
__global__ void k_scoref(const int* __restrict__ row, const int* __restrict__ col,
                         const float* __restrict__ h2, float* __restrict__ out, int E) {
    int e = blockIdx.x * 256 + threadIdx.x;
    if (e < E) {
        const float4* a = (const float4*)(h2 + (size_t)row[e] * 16);
        const float4* b = (const float4*)(h2 + (size_t)col[e] * 16);
        float d = 0.f;
        #pragma unroll
        for (int i = 0; i < 4; ++i) {
            float4 u = a[i], v = b[i];
            d += u.x * v.x + u.y * v.y + u.z * v.z + u.w * v.w;
        }
        out[e] = 1.0f / (1.0f + __expf(-d));
    }
}

extern "C" void kernel_launch(void* const* d_in, const int* in_sizes, int n_in,
                              void* d_out, int out_size, void* d_ws, size_t ws_size,
                              hipStream_t stream) {
    const float* x  = (const float*)d_in[0];
    const int*   ei = (const int*)d_in[1];
    const float* W1 = (const float*)d_in[2];
    const float* b1 = (const float*)d_in[3];
    const float* W2 = (const float*)d_in[4];
    const float* b2 = (const float*)d_in[5];

    const int N = in_sizes[0] / 128;   // 100000
    const int E = in_sizes[1] / 2;     // 3200000
    const int* row = ei;
    const int* col = ei + E;
    float* out = (float*)d_out;

    const int NBUK = (N + BSZ - 1) / BSZ;          // 782
    const int CN = (E + MAXCH - 1) / MAXCH;        // 1000 chunks
    const int CH = MAXCH;                          // 3200, multiple of 4

    char* ws = (char*)d_ws;
    size_t off = 0;
    auto alloc = [&](size_t bytes) { void* p = ws + off; off += (bytes + 255) & ~(size_t)255; return p; };
    float*  dinv  = (float*)alloc((size_t)N * 4);
    __half* ts1h  = (__half*)alloc((size_t)N * 32);    // also h2h after pGat1
    __half* ts2h  = (__half*)alloc((size_t)N * 32);
    int*    start = (int*)alloc((size_t)(N + 1) * 4);
    int*    gcur  = (int*)alloc((size_t)NBUK * 4);
    unsigned int* ebuf  = (unsigned int*)alloc((size_t)NBUK * CAPB * 4);   // 25.6 MB
    unsigned int* ebuf2 = (unsigned int*)alloc((size_t)NBUK * CAPB * 4);   // 25.6 MB
    const size_t need = off;    // ~59 MB at N=100k, E=3.2M

    // fixed-capacity guard: uniform input fills buckets to ~CAPB/2 (+-64 sigma)
    if (N <= 131072 && NBUK <= 1024 && CN <= MAXCHUNKS &&
        (size_t)E * 2 <= (size_t)NBUK * CAPB && ws_size >= need) {
        hipMemsetAsync(gcur, 0, (size_t)NBUK * 4, stream);
        pSort<<<CN, 1024, 0, stream>>>(row, col, gcur, ebuf, E, CH, NBUK);
        pS2G<<<NBUK, 512, 0, stream>>>(ebuf, gcur, x, W1, ebuf2, dinv, start, ts1h, N);
        pGat1<<<(N + 31) / 32, 256, 0, stream>>>(ebuf2, start, gcur, (const __half2*)ts1h,
                                                 dinv, b1, W2, (__half2*)ts2h, N);
        __half* h2h = ts1h;   // ts1h dead after pGat1
        pGat2<<<(N + 31) / 32, 256, 0, stream>>>(ebuf2, start, gcur, (const __half2*)ts2h,
                                                 dinv, b2, (__half2*)h2h, N);
        k_score<<<(E + 255) / 256, 256, 0, stream>>>(row, col, h2h, out, E);
    } else {
        // R2 fallback, fp32 buffers carved independently
        float* dinvF = (float*)ws;
        float* ts1F  = (float*)(ws + (size_t)N * 4);
        float* ts2F  = (float*)(ws + (size_t)N * 4 + (size_t)N * 64);
        hipMemsetAsync(dinvF, 0, (size_t)N * 4, stream);
        hipMemsetAsync(ts2F, 0, (size_t)N * 64, stream);
        k_countf<<<(E + 255) / 256, 256, 0, stream>>>(col, dinvF, E);
        k_dinvf<<<(N + 255) / 256, 256, 0, stream>>>(dinvF, N);
        k_gemm1f<<<(N + 255) / 256, 256, 0, stream>>>(x, W1, dinvF, ts1F, N);
        k_scatter<<<(E * 16) / 256, 256, 0, stream>>>(row, col, ts1F, ts2F, E);
        k_finalize<<<(N * 16 + 255) / 256, 256, 0, stream>>>(ts2F, ts1F, dinvF, b1, N, 1);
        k_gemm2f<<<N / 16, 256, 0, stream>>>(ts2F, W2, dinvF, ts1F, N);
        hipMemsetAsync(ts2F, 0, (size_t)N * 64, stream);
        k_scatter<<<(E * 16) / 256, 256, 0, stream>>>(row, col, ts1F, ts2F, E);
        k_finalize<<<(N * 16 + 255) / 256, 256, 0, stream>>>(ts2F, ts1F, dinvF, b2, N, 0);
        k_scoref<<<(E + 255) / 256, 256, 0, stream>>>(row, col, ts2F, out, E);
    }
}